// Round 6
// baseline (233.487 us; speedup 1.0000x reference)
//
#include <hip/hip_runtime.h>
#include <hip/hip_bf16.h>

// Problem constants
#define B 32
#define T 4096
#define E 1024
#define H 1024

// ws layout (in floats)
// qkv: p=0 -> v, p=1 -> k, p=2 -> q  (matches input order W_value, W_Key, W_Query)
#define OFF_QKV    0                       // 3 * 32 * 1024 = 98304
#define ECH        16
#define OFF_PART1  98304                   // 3 * ECH * 32 * 1024 = 1572864
#define OFF_SCORES (OFF_PART1 + 3*ECH*32*1024)   // 32 * 4096 = 131072
#define ATTN_STRIDE 4104
#define OFF_ATTN   (OFF_SCORES + 32*4096)  // 32 * 4104 = 131328
#define NTC        64                      // t-chunks for PV (64 rows each)
#define OFF_PART2  (OFF_ATTN + 32*ATTN_STRIDE)   // 32 * NTC * 1024 = 2097152

// ---------------------------------------------------------------------------
// Kernel 1: projection partial sums (UNCHANGED round-3 anchor).
// grid (ECH, 16, 3), block 256.
__global__ void proj_partial(const float* __restrict__ x,
                             const float* __restrict__ Wv,
                             const float* __restrict__ Wk,
                             const float* __restrict__ Wq,
                             float* __restrict__ part) {
    const int ec = blockIdx.x;
    const int hc = blockIdx.y;
    const int p  = blockIdx.z;
    const float* __restrict__ W = (p == 0) ? Wv : ((p == 1) ? Wk : Wq);

    const int wave = threadIdx.x >> 6;
    const int lane = threadIdx.x & 63;
    const int h  = hc * 64 + lane;
    const int b0 = wave * 8;
    const int e0 = ec * 64;

    float acc[8] = {0.f, 0.f, 0.f, 0.f, 0.f, 0.f, 0.f, 0.f};

    for (int eg = 0; eg < 16; ++eg) {
        const int e = e0 + eg * 4;
        const float w0 = W[(size_t)(e + 0) * H + h];
        const float w1 = W[(size_t)(e + 1) * H + h];
        const float w2 = W[(size_t)(e + 2) * H + h];
        const float w3 = W[(size_t)(e + 3) * H + h];
#pragma unroll
        for (int j = 0; j < 8; ++j) {
            const float4 xv = *reinterpret_cast<const float4*>(&x[(b0 + j) * E + e]);
            acc[j] += xv.x * w0 + xv.y * w1 + xv.z * w2 + xv.w * w3;
        }
    }
#pragma unroll
    for (int j = 0; j < 8; ++j) {
        part[((size_t)(p * ECH + ec) * B + (b0 + j)) * H + h] = acc[j];
    }
}

// ---------------------------------------------------------------------------
// Kernel 2: reduce projection partials -> qkv (UNCHANGED). grid 384, block 256.
__global__ void proj_reduce(const float* __restrict__ part,
                            float* __restrict__ qkv) {
    const int idx = blockIdx.x * 256 + threadIdx.x;
    const int p = idx >> 15;
    const int r = idx & 32767;
    float s = 0.f;
#pragma unroll
    for (int ec = 0; ec < ECH; ++ec)
        s += part[(size_t)(p * ECH + ec) * (B * H) + r];
    qkv[(size_t)p * (B * H) + r] = s;
}

// ---------------------------------------------------------------------------
// Kernel 3: scores[b][t] = dot(key_cache[b][t][:], q[b][:]).
// grid (64, B), block 256 (4 waves). Persistent blocks: each block keeps
// q[b] in registers and grid-strides over 8 t-octets (stride 64 octets).
// Per-octet inner work identical to round-3 anchor (2 rows/wave).
__global__ void scores_kernel(const float* __restrict__ kc,
                              const float* __restrict__ q,
                              float* __restrict__ scores) {
    const int b = blockIdx.y;
    const int wave = threadIdx.x >> 6;
    const int lane = threadIdx.x & 63;

    const float4* __restrict__ q4 = reinterpret_cast<const float4*>(q + (size_t)b * H);
    float4 qv[4];
#pragma unroll
    for (int g = 0; g < 4; ++g) qv[g] = q4[g * 64 + lane];

    for (int j = 0; j < 8; ++j) {
        const int oct = blockIdx.x + j * 64;          // 0..511
#pragma unroll
        for (int r = 0; r < 2; ++r) {
            const int t = oct * 8 + wave * 2 + r;
            const float4* __restrict__ row =
                reinterpret_cast<const float4*>(kc + ((size_t)b * T + t) * H);
            float acc = 0.f;
#pragma unroll
            for (int g = 0; g < 4; ++g) {
                const float4 kv = row[g * 64 + lane];
                acc += kv.x * qv[g].x + kv.y * qv[g].y + kv.z * qv[g].z + kv.w * qv[g].w;
            }
#pragma unroll
            for (int m = 32; m; m >>= 1) acc += __shfl_xor(acc, m, 64);
            if (lane == 0) scores[(size_t)b * T + t] = acc;
        }
    }
}

// ---------------------------------------------------------------------------
// Kernel 4: softmax over (T+1) scores per batch (UNCHANGED). grid B, block 256.
__global__ void softmax_kernel(const float* __restrict__ scores,
                               const float* __restrict__ qkv,
                               float* __restrict__ attn) {
    __shared__ float red[256];
    const int b = blockIdx.x, tid = threadIdx.x;
    const float* __restrict__ qp = qkv + 2 * (B * H) + (size_t)b * H;
    const float* __restrict__ kp = qkv + 1 * (B * H) + (size_t)b * H;

    const float4 qv = reinterpret_cast<const float4*>(qp)[tid];
    const float4 kv = reinterpret_cast<const float4*>(kp)[tid];
    red[tid] = qv.x * kv.x + qv.y * kv.y + qv.z * kv.z + qv.w * kv.w;
    __syncthreads();
    for (int s = 128; s; s >>= 1) {
        if (tid < s) red[tid] += red[tid + s];
        __syncthreads();
    }
    const float s_last = red[0];
    __syncthreads();

    float sc[16];
    const float* __restrict__ srow = scores + (size_t)b * T;
    float mx = s_last;
#pragma unroll
    for (int i = 0; i < 16; ++i) {
        sc[i] = srow[i * 256 + tid];
        mx = fmaxf(mx, sc[i]);
    }
    red[tid] = mx;
    __syncthreads();
    for (int s = 128; s; s >>= 1) {
        if (tid < s) red[tid] = fmaxf(red[tid], red[tid + s]);
        __syncthreads();
    }
    mx = red[0];
    __syncthreads();

    float sum = 0.f;
#pragma unroll
    for (int i = 0; i < 16; ++i) {
        sc[i] = expf(sc[i] - mx);
        sum += sc[i];
    }
    const float e_last = expf(s_last - mx);
    if (tid == 0) sum += e_last;
    red[tid] = sum;
    __syncthreads();
    for (int s = 128; s; s >>= 1) {
        if (tid < s) red[tid] += red[tid + s];
        __syncthreads();
    }
    const float inv = 1.f / red[0];

    float* __restrict__ arow = attn + (size_t)b * ATTN_STRIDE;
#pragma unroll
    for (int i = 0; i < 16; ++i) arow[i * 256 + tid] = sc[i] * inv;
    if (tid == 0) arow[T] = e_last * inv;
}

// ---------------------------------------------------------------------------
// Kernel 5: PV partials. grid (NTC=64, B) = 2048 blocks (8/CU), block 256.
// Chunk of 64 rows; inner loop identical to round-3 anchor, unroll 4.
__global__ void pv_partial(const float* __restrict__ vc,
                           const float* __restrict__ attn,
                           float* __restrict__ part2) {
    __shared__ float as[T / NTC];     // 64 attn weights
    const int tc = blockIdx.x, b = blockIdx.y, tid = threadIdx.x;
    const int t0 = tc * (T / NTC);
    if (tid < (T / NTC)) as[tid] = attn[(size_t)b * ATTN_STRIDE + t0 + tid];
    __syncthreads();

    const float4* __restrict__ vrow =
        reinterpret_cast<const float4*>(vc + ((size_t)b * T + t0) * H);
    float4 acc = {0.f, 0.f, 0.f, 0.f};
#pragma unroll 4
    for (int t = 0; t < (T / NTC); ++t) {
        const float a = as[t];
        const float4 vv = vrow[(size_t)t * 256 + tid];
        acc.x += a * vv.x; acc.y += a * vv.y;
        acc.z += a * vv.z; acc.w += a * vv.w;
    }
    reinterpret_cast<float4*>(part2 + ((size_t)b * NTC + tc) * H)[tid] = acc;
}

// ---------------------------------------------------------------------------
// Kernel 6: finalize (64 partials now). grid 128, block 256.
__global__ void finalize_kernel(const float* __restrict__ part2,
                                const float* __restrict__ attn,
                                const float* __restrict__ qkv,
                                const float* __restrict__ x,
                                float* __restrict__ out) {
    const int idx = blockIdx.x * 256 + threadIdx.x;  // 0..32767
    const int b = idx >> 10;
    const int h = idx & 1023;
    float s = 0.f;
#pragma unroll
    for (int tc = 0; tc < NTC; ++tc)
        s += part2[((size_t)b * NTC + tc) * H + h];
    const float a_last = attn[(size_t)b * ATTN_STRIDE + T];
    const float v = qkv[(size_t)b * H + h];   // p=0 slot is value projection
    out[idx] = (s + a_last * v) * (1.f / 32.f) + x[idx];
}

// ---------------------------------------------------------------------------
extern "C" void kernel_launch(void* const* d_in, const int* in_sizes, int n_in,
                              void* d_out, int out_size, void* d_ws, size_t ws_size,
                              hipStream_t stream) {
    const float* x  = (const float*)d_in[0];
    const float* kc = (const float*)d_in[1];
    const float* vc = (const float*)d_in[2];
    const float* Wv = (const float*)d_in[3];
    const float* Wk = (const float*)d_in[4];
    const float* Wq = (const float*)d_in[5];
    float* out = (float*)d_out;
    float* ws  = (float*)d_ws;

    float* qkv    = ws + OFF_QKV;
    float* part1  = ws + OFF_PART1;
    float* scores = ws + OFF_SCORES;
    float* attn   = ws + OFF_ATTN;
    float* part2  = ws + OFF_PART2;

    hipLaunchKernelGGL(proj_partial, dim3(ECH, 16, 3), dim3(256), 0, stream,
                       x, Wv, Wk, Wq, part1);
    hipLaunchKernelGGL(proj_reduce, dim3(384), dim3(256), 0, stream,
                       part1, qkv);
    hipLaunchKernelGGL(scores_kernel, dim3(64, B), dim3(256), 0, stream,
                       kc, qkv + 2 * (B * H), scores);
    hipLaunchKernelGGL(softmax_kernel, dim3(B), dim3(256), 0, stream,
                       scores, qkv, attn);
    hipLaunchKernelGGL(pv_partial, dim3(NTC, B), dim3(256), 0, stream,
                       vc, attn, part2);
    hipLaunchKernelGGL(finalize_kernel, dim3(128), dim3(256), 0, stream,
                       part2, attn, qkv, x, out);
}

// Round 7
// 152.896 us; speedup vs baseline: 1.5271x; 1.5271x over previous
//
#include <hip/hip_runtime.h>
#include <hip/hip_bf16.h>

// Problem constants
#define B 32
#define T 4096
#define E 1024
#define H 1024

// ws layout (in floats)
// qkv: p=0 -> v, p=1 -> k, p=2 -> q  (matches input order W_value, W_Key, W_Query)
#define OFF_QKV    0                       // 3 * 32 * 1024 = 98304
#define ECH        16
#define OFF_PART1  98304                   // 3 * ECH * 32 * 1024 = 1572864
#define OFF_SCORES (OFF_PART1 + 3*ECH*32*1024)   // 32 * 4096 = 131072
#define ATTN_STRIDE 4104
#define OFF_ATTN   (OFF_SCORES + 32*4096)  // 32 * 4104 = 131328
#define NTC        32                      // t-chunks for PV (128 rows each)
#define OFF_PART2  (OFF_ATTN + 32*ATTN_STRIDE)   // 32 * NTC * 1024 = 1048576
#define OFF_CSUM   (OFF_PART2 + B * NTC * H)     // 32 * NTC = 1024

// ---------------------------------------------------------------------------
// Kernel 1: projection partial sums (UNCHANGED round-3 anchor).
// grid (ECH, 16, 3), block 256.
__global__ void proj_partial(const float* __restrict__ x,
                             const float* __restrict__ Wv,
                             const float* __restrict__ Wk,
                             const float* __restrict__ Wq,
                             float* __restrict__ part) {
    const int ec = blockIdx.x;
    const int hc = blockIdx.y;
    const int p  = blockIdx.z;
    const float* __restrict__ W = (p == 0) ? Wv : ((p == 1) ? Wk : Wq);

    const int wave = threadIdx.x >> 6;
    const int lane = threadIdx.x & 63;
    const int h  = hc * 64 + lane;
    const int b0 = wave * 8;
    const int e0 = ec * 64;

    float acc[8] = {0.f, 0.f, 0.f, 0.f, 0.f, 0.f, 0.f, 0.f};

    for (int eg = 0; eg < 16; ++eg) {
        const int e = e0 + eg * 4;
        const float w0 = W[(size_t)(e + 0) * H + h];
        const float w1 = W[(size_t)(e + 1) * H + h];
        const float w2 = W[(size_t)(e + 2) * H + h];
        const float w3 = W[(size_t)(e + 3) * H + h];
#pragma unroll
        for (int j = 0; j < 8; ++j) {
            const float4 xv = *reinterpret_cast<const float4*>(&x[(b0 + j) * E + e]);
            acc[j] += xv.x * w0 + xv.y * w1 + xv.z * w2 + xv.w * w3;
        }
    }
#pragma unroll
    for (int j = 0; j < 8; ++j) {
        part[((size_t)(p * ECH + ec) * B + (b0 + j)) * H + h] = acc[j];
    }
}

// ---------------------------------------------------------------------------
// Kernel 2: reduce projection partials -> qkv (UNCHANGED). grid 384, block 256.
__global__ void proj_reduce(const float* __restrict__ part,
                            float* __restrict__ qkv) {
    const int idx = blockIdx.x * 256 + threadIdx.x;
    const int p = idx >> 15;
    const int r = idx & 32767;
    float s = 0.f;
#pragma unroll
    for (int ec = 0; ec < ECH; ++ec)
        s += part[(size_t)(p * ECH + ec) * (B * H) + r];
    qkv[(size_t)p * (B * H) + r] = s;
}

// ---------------------------------------------------------------------------
// Kernel 3: scores (UNCHANGED round-3 anchor).
// grid (T/8, B), block 256 (4 waves); each wave handles 2 rows; q in regs.
__global__ void scores_kernel(const float* __restrict__ kc,
                              const float* __restrict__ q,
                              float* __restrict__ scores) {
    const int b = blockIdx.y;
    const int wave = threadIdx.x >> 6;
    const int lane = threadIdx.x & 63;

    const float4* __restrict__ q4 = reinterpret_cast<const float4*>(q + (size_t)b * H);
    float4 qv[4];
#pragma unroll
    for (int g = 0; g < 4; ++g) qv[g] = q4[g * 64 + lane];

#pragma unroll
    for (int r = 0; r < 2; ++r) {
        const int t = blockIdx.x * 8 + wave * 2 + r;
        const float4* __restrict__ row =
            reinterpret_cast<const float4*>(kc + ((size_t)b * T + t) * H);
        float acc = 0.f;
#pragma unroll
        for (int g = 0; g < 4; ++g) {
            const float4 kv = row[g * 64 + lane];
            acc += kv.x * qv[g].x + kv.y * qv[g].y + kv.z * qv[g].z + kv.w * qv[g].w;
        }
#pragma unroll
        for (int m = 32; m; m >>= 1) acc += __shfl_xor(acc, m, 64);
        if (lane == 0) scores[(size_t)b * T + t] = acc;
    }
}

// ---------------------------------------------------------------------------
// Kernel 4: softmax over (T+1) scores per batch (UNCHANGED). grid B, block 256.
__global__ void softmax_kernel(const float* __restrict__ scores,
                               const float* __restrict__ qkv,
                               float* __restrict__ attn) {
    __shared__ float red[256];
    const int b = blockIdx.x, tid = threadIdx.x;
    const float* __restrict__ qp = qkv + 2 * (B * H) + (size_t)b * H;
    const float* __restrict__ kp = qkv + 1 * (B * H) + (size_t)b * H;

    const float4 qv = reinterpret_cast<const float4*>(qp)[tid];
    const float4 kv = reinterpret_cast<const float4*>(kp)[tid];
    red[tid] = qv.x * kv.x + qv.y * kv.y + qv.z * kv.z + qv.w * kv.w;
    __syncthreads();
    for (int s = 128; s; s >>= 1) {
        if (tid < s) red[tid] += red[tid + s];
        __syncthreads();
    }
    const float s_last = red[0];
    __syncthreads();

    float sc[16];
    const float* __restrict__ srow = scores + (size_t)b * T;
    float mx = s_last;
#pragma unroll
    for (int i = 0; i < 16; ++i) {
        sc[i] = srow[i * 256 + tid];
        mx = fmaxf(mx, sc[i]);
    }
    red[tid] = mx;
    __syncthreads();
    for (int s = 128; s; s >>= 1) {
        if (tid < s) red[tid] = fmaxf(red[tid], red[tid + s]);
        __syncthreads();
    }
    mx = red[0];
    __syncthreads();

    float sum = 0.f;
#pragma unroll
    for (int i = 0; i < 16; ++i) {
        sc[i] = expf(sc[i] - mx);
        sum += sc[i];
    }
    const float e_last = expf(s_last - mx);
    if (tid == 0) sum += e_last;
    red[tid] = sum;
    __syncthreads();
    for (int s = 128; s; s >>= 1) {
        if (tid < s) red[tid] += red[tid + s];
        __syncthreads();
    }
    const float inv = 1.f / red[0];

    float* __restrict__ arow = attn + (size_t)b * ATTN_STRIDE;
#pragma unroll
    for (int i = 0; i < 16; ++i) arow[i * 256 + tid] = sc[i] * inv;
    if (tid == 0) arow[T] = e_last * inv;
}

// ---------------------------------------------------------------------------
// Kernel 5: PV partials with EXACT zero-chunk skipping.
// grid (NTC=32, B), block 256. Chunk weight-sum == 0.0f (all weights exactly
// underflowed to +0) => the chunk's contribution is exactly zero: skip the
// 512 KB V read entirely. csum[b][tc] is ALWAYS written (deterministic).
__global__ void pv_partial(const float* __restrict__ vc,
                           const float* __restrict__ attn,
                           float* __restrict__ part2,
                           float* __restrict__ csum) {
    __shared__ float as[T / NTC];     // 128 attn weights
    __shared__ float wsum[2];
    const int tc = blockIdx.x, b = blockIdx.y, tid = threadIdx.x;
    const int t0 = tc * (T / NTC);
    if (tid < (T / NTC)) as[tid] = attn[(size_t)b * ATTN_STRIDE + t0 + tid];
    __syncthreads();

    // chunk weight sum: 2 waves reduce the 128 loaded weights
    if (tid < (T / NTC)) {
        float w = as[tid];
#pragma unroll
        for (int m = 32; m; m >>= 1) w += __shfl_xor(w, m, 64);
        if ((tid & 63) == 0) wsum[tid >> 6] = w;
    }
    __syncthreads();
    const float total = wsum[0] + wsum[1];
    if (tid == 0) csum[(size_t)b * NTC + tc] = total;
    if (total <= 0.0f) return;    // weights >= 0: sum==0 iff all exactly 0

    const float4* __restrict__ vrow =
        reinterpret_cast<const float4*>(vc + ((size_t)b * T + t0) * H);
    float4 acc = {0.f, 0.f, 0.f, 0.f};
#pragma unroll 4
    for (int t = 0; t < (T / NTC); ++t) {
        const float a = as[t];
        const float4 vv = vrow[(size_t)t * 256 + tid];
        acc.x += a * vv.x; acc.y += a * vv.y;
        acc.z += a * vv.z; acc.w += a * vv.w;
    }
    reinterpret_cast<float4*>(part2 + ((size_t)b * NTC + tc) * H)[tid] = acc;
}

// ---------------------------------------------------------------------------
// Kernel 6: finalize; sums only chunks with csum > 0 (skipped chunks never
// wrote part2 and contribute exactly zero). grid 128, block 256.
// b = blockIdx.x >> 2 is uniform per block.
__global__ void finalize_kernel(const float* __restrict__ part2,
                                const float* __restrict__ attn,
                                const float* __restrict__ qkv,
                                const float* __restrict__ x,
                                const float* __restrict__ csum,
                                float* __restrict__ out) {
    __shared__ float cs[NTC];
    const int idx = blockIdx.x * 256 + threadIdx.x;  // 0..32767
    const int b = idx >> 10;
    const int h = idx & 1023;
    if (threadIdx.x < NTC) cs[threadIdx.x] = csum[(size_t)b * NTC + threadIdx.x];
    __syncthreads();

    float s = 0.f;
    for (int tc = 0; tc < NTC; ++tc)
        if (cs[tc] > 0.0f)
            s += part2[((size_t)b * NTC + tc) * H + h];
    const float a_last = attn[(size_t)b * ATTN_STRIDE + T];
    const float v = qkv[(size_t)b * H + h];   // p=0 slot is value projection
    out[idx] = (s + a_last * v) * (1.f / 32.f) + x[idx];
}

// ---------------------------------------------------------------------------
extern "C" void kernel_launch(void* const* d_in, const int* in_sizes, int n_in,
                              void* d_out, int out_size, void* d_ws, size_t ws_size,
                              hipStream_t stream) {
    const float* x  = (const float*)d_in[0];
    const float* kc = (const float*)d_in[1];
    const float* vc = (const float*)d_in[2];
    const float* Wv = (const float*)d_in[3];
    const float* Wk = (const float*)d_in[4];
    const float* Wq = (const float*)d_in[5];
    float* out = (float*)d_out;
    float* ws  = (float*)d_ws;

    float* qkv    = ws + OFF_QKV;
    float* part1  = ws + OFF_PART1;
    float* scores = ws + OFF_SCORES;
    float* attn   = ws + OFF_ATTN;
    float* part2  = ws + OFF_PART2;
    float* csum   = ws + OFF_CSUM;

    hipLaunchKernelGGL(proj_partial, dim3(ECH, 16, 3), dim3(256), 0, stream,
                       x, Wv, Wk, Wq, part1);
    hipLaunchKernelGGL(proj_reduce, dim3(384), dim3(256), 0, stream,
                       part1, qkv);
    hipLaunchKernelGGL(scores_kernel, dim3(T / 8, B), dim3(256), 0, stream,
                       kc, qkv + 2 * (B * H), scores);
    hipLaunchKernelGGL(softmax_kernel, dim3(B), dim3(256), 0, stream,
                       scores, qkv, attn);
    hipLaunchKernelGGL(pv_partial, dim3(NTC, B), dim3(256), 0, stream,
                       vc, attn, part2, csum);
    hipLaunchKernelGGL(finalize_kernel, dim3(128), dim3(256), 0, stream,
                       part2, attn, qkv, x, csum, out);
}